// Round 1
// baseline (861.652 us; speedup 1.0000x reference)
//
#include <hip/hip_runtime.h>
#include <hip/hip_bf16.h>

// EncoderLayer on MI355X (gfx950).
// Pipeline: cast/transpose -> QKV GEMM (bf16 MFMA) -> V-transpose -> flash attn
//           -> proj GEMM (+bc +resid) -> LN1 -> FFN1 GEMM (+b1, relu) -> FFN2 GEMM (+b2 +resid) -> LN2.
// Workspace layout (needs 160 MB):
//   [0,16M)   xb (bf16 x)          -> reused as attnb (attention out, bf16)
//   [16,22M)  wqkvt  (Wq|Wk|Wv)^T bf16   [3072][1024]
//   [22,24M)  wct    Wc^T bf16            [1024][1024]
//   [24,28M)  w1t    W1^T bf16            [2048][1024]
//   [28,32M)  w2t    W2^T bf16            [1024][2048]
//   [32,80M)  qkv bf16 [8192][3072]  -> after attention reused: y1 f32 @32M, h1b bf16 @64M
//   [80,96M)  vt  bf16 [4*1024][2048]  (V^T per batch: [(b,h,d)][token])
//   [96,128M) h1f f32 (LN1 out, residual for FFN2)
//   [128,160M) midb bf16 [8192][2048]

#define DEV __device__ __forceinline__

using s16x8 = __attribute__((ext_vector_type(8))) short;   // 8 bf16 (4 VGPR) MFMA frag
using f32x4 = __attribute__((ext_vector_type(4))) float;

DEV unsigned short f2bf(float f) {            // f32 -> bf16 RNE (no NaNs in this workload)
  unsigned u = __float_as_uint(f);
  u += 0x7fffu + ((u >> 16) & 1u);
  return (unsigned short)(u >> 16);
}
DEV unsigned pack2bf(float a, float b) {
  return (unsigned)f2bf(a) | ((unsigned)f2bf(b) << 16);
}

typedef __attribute__((address_space(3))) unsigned lds_u32_t;
typedef const __attribute__((address_space(1))) unsigned glb_u32_t;

// async global->LDS, 16B per lane; lds dst must be wave-uniform (HW adds lane*16)
DEV void gld_lds16(const void* g, void* l) {
  __builtin_amdgcn_global_load_lds((glb_u32_t*)g, (lds_u32_t*)l, 16, 0, 0);
}

// ---------------------------------------------------------------------------
// GEMM: C[M][N] = A[M][K] * Bt[N][K]^T  (both bf16 row-major), fp32 acc.
// 128x128 tile, BK=32, 4 waves (2x2), each wave 64x64 = 4x4 16x16x32 frags.
// ---------------------------------------------------------------------------
template<int RELU, int RESID, int OUTF>
__global__ __launch_bounds__(256)
void gemm_bt(const unsigned short* __restrict__ A, const unsigned short* __restrict__ Bt,
             unsigned short* __restrict__ Cb, float* __restrict__ Cf,
             const float* __restrict__ bias, const float* __restrict__ resid,
             int M, int N, int K)
{
  __shared__ unsigned short As[128 * 32];
  __shared__ unsigned short Bs[128 * 32];
  const int tid  = threadIdx.x;
  const int wave = tid >> 6, lane = tid & 63;
  const int g = lane >> 4, q = lane & 15;
  const int m0 = blockIdx.y * 128, n0 = blockIdx.x * 128;
  const int wr = wave >> 1, wc = wave & 1;

  f32x4 acc[4][4] = {};

  const int i0 = wave * 512 + lane * 8;        // pass 0 element index in 128x32 tile
  const int i1 = 2048 + i0;                    // pass 1

  for (int kt = 0; kt < K; kt += 32) {
    gld_lds16(A  + (size_t)(m0 + (i0 >> 5)) * K + kt + (i0 & 31), As + wave * 512);
    gld_lds16(Bt + (size_t)(n0 + (i0 >> 5)) * K + kt + (i0 & 31), Bs + wave * 512);
    gld_lds16(A  + (size_t)(m0 + (i1 >> 5)) * K + kt + (i1 & 31), As + 2048 + wave * 512);
    gld_lds16(Bt + (size_t)(n0 + (i1 >> 5)) * K + kt + (i1 & 31), Bs + 2048 + wave * 512);
    __syncthreads();                            // drains vmcnt for global_load_lds
    s16x8 a[4], b[4];
#pragma unroll
    for (int m = 0; m < 4; ++m)
      a[m] = *(const s16x8*)(As + (wr * 64 + m * 16 + q) * 32 + g * 8);
#pragma unroll
    for (int n = 0; n < 4; ++n)
      b[n] = *(const s16x8*)(Bs + (wc * 64 + n * 16 + q) * 32 + g * 8);
#pragma unroll
    for (int m = 0; m < 4; ++m)
#pragma unroll
      for (int n = 0; n < 4; ++n)
        acc[m][n] = __builtin_amdgcn_mfma_f32_16x16x32_bf16(a[m], b[n], acc[m][n], 0, 0, 0);
    __syncthreads();
  }

  // epilogue: C/D layout col = lane&15, row = (lane>>4)*4 + reg
#pragma unroll
  for (int n = 0; n < 4; ++n) {
    const int col = n0 + wc * 64 + n * 16 + q;
    const float bv = bias ? bias[col] : 0.0f;
#pragma unroll
    for (int m = 0; m < 4; ++m) {
      const int row0 = m0 + wr * 64 + m * 16 + g * 4;
#pragma unroll
      for (int r = 0; r < 4; ++r) {
        float v = acc[m][n][r] + bv;
        if (RELU) v = fmaxf(v, 0.0f);
        if (RESID) v += resid[(size_t)(row0 + r) * N + col];
        if (OUTF) Cf[(size_t)(row0 + r) * N + col] = v;
        else      Cb[(size_t)(row0 + r) * N + col] = f2bf(v);
      }
    }
  }
}

// ---------------------------------------------------------------------------
// Flash attention. grid (32 q-tiles, 64 bh). 4 waves/block; each wave owns 16 q rows.
// S^T = mfma(K, Q): lane holds one query (q = lane&15), kv = m2*16 + (lane>>4)*4 + r.
// O^T = mfma(V^T, P^T): accumulator col = q = lane&15 (matches softmax state).
// P crosses lanes through a per-wave XOR-swizzled LDS tile [16 q][64 kv] bf16.
// ---------------------------------------------------------------------------
__global__ __launch_bounds__(256)
void attn_kernel(const unsigned short* __restrict__ qkv,   // [8192][3072] Q|K|V
                 const unsigned short* __restrict__ vt,    // [(b*16+h)*64+d][2048]
                 const float* __restrict__ mask,           // [4][2048][2048]
                 unsigned short* __restrict__ outb)        // [8192][1024]
{
  __shared__ unsigned short Pl[4][1024];                   // 2KB per wave
  const int tid = threadIdx.x, wave = tid >> 6, lane = tid & 63;
  const int g = lane >> 4, q = lane & 15;
  const int qt = blockIdx.x, bh = blockIdx.y;
  const int b = bh >> 4, h = bh & 15;
  const int qrow = qt * 64 + wave * 16;
  const size_t tok0 = (size_t)b * 2048;

  const unsigned short* Qp = qkv + (tok0 + qrow + q) * 3072 + h * 64;
  const unsigned short* Kp = qkv + tok0 * 3072 + 1024 + h * 64;
  const unsigned short* Vp = vt + (size_t)bh * 64 * 2048;
  const float* Mp = mask + ((size_t)b * 2048 + qrow + q) * 2048;

  const s16x8 bq0 = *(const s16x8*)(Qp + g * 8);           // Q B-frag, kb=0
  const s16x8 bq1 = *(const s16x8*)(Qp + 32 + g * 8);      // kb=1

  f32x4 ot[4] = {};
  float mrun = -3.0e38f, lsum = 0.0f;
  char* Pw = (char*)&Pl[wave][0];

  for (int kv0 = 0; kv0 < 2048; kv0 += 64) {
    // S^T tile: 4 kv-blocks x (K=64 as 2 mfma)
    f32x4 st[4] = {};
#pragma unroll
    for (int m2 = 0; m2 < 4; ++m2) {
      const unsigned short* kp = Kp + (size_t)(kv0 + m2 * 16 + q) * 3072 + g * 8;
      const s16x8 ak0 = *(const s16x8*)kp;
      const s16x8 ak1 = *(const s16x8*)(kp + 32);
      st[m2] = __builtin_amdgcn_mfma_f32_16x16x32_bf16(ak0, bq0, st[m2], 0, 0, 0);
      st[m2] = __builtin_amdgcn_mfma_f32_16x16x32_bf16(ak1, bq1, st[m2], 0, 0, 0);
    }
    // scale + mask, tile max
    float tmax = -3.0e38f;
#pragma unroll
    for (int m2 = 0; m2 < 4; ++m2) {
      const f32x4 mk = *(const f32x4*)(Mp + kv0 + m2 * 16 + g * 4);
#pragma unroll
      for (int r = 0; r < 4; ++r) {
        st[m2][r] = st[m2][r] * 0.125f + mk[r];
        tmax = fmaxf(tmax, st[m2][r]);
      }
    }
    tmax = fmaxf(tmax, __shfl_xor(tmax, 16));
    tmax = fmaxf(tmax, __shfl_xor(tmax, 32));
    const float mnew  = fmaxf(mrun, tmax);
    const float alpha = __expf(mrun - mnew);
    mrun = mnew;

    float rsum = 0.0f;
#pragma unroll
    for (int m2 = 0; m2 < 4; ++m2) {
#pragma unroll
      for (int r = 0; r < 4; ++r) {
        st[m2][r] = __expf(st[m2][r] - mnew);
        rsum += st[m2][r];
      }
      // write P[q][kv] (4 consecutive kv) to LDS, 16B-block XOR swizzle by row
      const int bir  = m2 * 32 + g * 8;
      const int addr = q * 128 + (((bir >> 4) ^ (q & 7)) << 4) + (bir & 15);
      uint2 pk;
      pk.x = pack2bf(st[m2][0], st[m2][1]);
      pk.y = pack2bf(st[m2][2], st[m2][3]);
      *(uint2*)(Pw + addr) = pk;
    }
    rsum += __shfl_xor(rsum, 16);
    rsum += __shfl_xor(rsum, 32);
    lsum = lsum * alpha + rsum;
#pragma unroll
    for (int m = 0; m < 4; ++m) {
      ot[m][0] *= alpha; ot[m][1] *= alpha; ot[m][2] *= alpha; ot[m][3] *= alpha;
    }
    // O^T += V^T * P^T   (same-wave LDS write->read: DS FIFO order, no barrier)
#pragma unroll
    for (int kb = 0; kb < 2; ++kb) {
      const int blk = (kb * 4 + g) ^ (q & 7);
      const s16x8 pb = *(const s16x8*)(Pw + q * 128 + blk * 16);
#pragma unroll
      for (int m = 0; m < 4; ++m) {
        const s16x8 av = *(const s16x8*)(Vp + (size_t)(m * 16 + q) * 2048 + kv0 + kb * 32 + g * 8);
        ot[m] = __builtin_amdgcn_mfma_f32_16x16x32_bf16(av, pb, ot[m], 0, 0, 0);
      }
    }
  }

  // finalize: O[q][d] = ot/lsum; transpose through LDS for coalesced 16B stores
  const float inv = 1.0f / lsum;
#pragma unroll
  for (int m = 0; m < 4; ++m) {
    const int bir  = m * 32 + g * 8;
    const int addr = q * 128 + (((bir >> 4) ^ (q & 7)) << 4) + (bir & 15);
    uint2 pk;
    pk.x = pack2bf(ot[m][0] * inv, ot[m][1] * inv);
    pk.y = pack2bf(ot[m][2] * inv, ot[m][3] * inv);
    *(uint2*)(Pw + addr) = pk;
  }
#pragma unroll
  for (int p = 0; p < 2; ++p) {
    const int c  = p * 64 + lane;
    const int qq = c >> 3, cc = c & 7;
    const int blk = cc ^ (qq & 7);
    const s16x8 vv = *(const s16x8*)(Pw + qq * 128 + blk * 16);
    *(s16x8*)(outb + (tok0 + qt * 64 + wave * 16 + qq) * 1024 + h * 64 + cc * 8) = vv;
  }
}

// ---------------------------------------------------------------------------
// Row LayerNorm over D=1024. One 256-thread block per row. In-place safe.
// ---------------------------------------------------------------------------
__global__ __launch_bounds__(256)
void ln_kernel(const float* __restrict__ in, float* __restrict__ outf,
               unsigned short* __restrict__ outb,
               const float* __restrict__ gam, const float* __restrict__ bet)
{
  __shared__ float red[8];
  const int row = blockIdx.x, tid = threadIdx.x;
  const f32x4 v = *(const f32x4*)(in + (size_t)row * 1024 + tid * 4);
  float s  = v[0] + v[1] + v[2] + v[3];
  float ss = v[0]*v[0] + v[1]*v[1] + v[2]*v[2] + v[3]*v[3];
#pragma unroll
  for (int o = 1; o < 64; o <<= 1) { s += __shfl_xor(s, o); ss += __shfl_xor(ss, o); }
  if ((tid & 63) == 0) { red[tid >> 6] = s; red[4 + (tid >> 6)] = ss; }
  __syncthreads();
  s  = red[0] + red[1] + red[2] + red[3];
  ss = red[4] + red[5] + red[6] + red[7];
  const float mean = s * (1.0f / 1024.0f);
  const float var  = ss * (1.0f / 1024.0f) - mean * mean;
  const float rstd = rsqrtf(var + 1e-5f);
  const f32x4 gm = *(const f32x4*)(gam + tid * 4);
  const f32x4 bt = *(const f32x4*)(bet + tid * 4);
  f32x4 o;
#pragma unroll
  for (int j = 0; j < 4; ++j) o[j] = (v[j] - mean) * rstd * gm[j] + bt[j];
  if (outf) *(f32x4*)(outf + (size_t)row * 1024 + tid * 4) = o;
  if (outb) {
    uint2 pk; pk.x = pack2bf(o[0], o[1]); pk.y = pack2bf(o[2], o[3]);
    *(uint2*)(outb + (size_t)row * 1024 + tid * 4) = pk;
  }
}

// f32 [R][C] -> bf16 [C][R]
__global__ __launch_bounds__(256)
void tcast_kernel(const float* __restrict__ in, unsigned short* __restrict__ out, int R, int C)
{
  __shared__ float t[32][33];
  const int tx = threadIdx.x & 31, ty = threadIdx.x >> 5;
  const int c0 = blockIdx.x * 32, r0 = blockIdx.y * 32;
#pragma unroll
  for (int k = 0; k < 4; ++k)
    t[ty + k * 8][tx] = in[(size_t)(r0 + ty + k * 8) * C + c0 + tx];
  __syncthreads();
#pragma unroll
  for (int k = 0; k < 4; ++k)
    out[(size_t)(c0 + ty + k * 8) * R + r0 + tx] = f2bf(t[tx][ty + k * 8]);
}

// V part of qkv (cols 2048..3071, per batch) -> vt[(b*16+h)*64+d][token]
__global__ __launch_bounds__(256)
void tv_kernel(const unsigned short* __restrict__ qkv, unsigned short* __restrict__ vt)
{
  __shared__ unsigned short t[32][33];
  const int tx = threadIdx.x & 31, ty = threadIdx.x >> 5;
  const int c0 = blockIdx.x * 32, r0 = blockIdx.y * 32, b = blockIdx.z;
  const unsigned short* in = qkv + (size_t)b * 2048 * 3072 + 2048;
  unsigned short* out = vt + (size_t)b * 1024 * 2048;
#pragma unroll
  for (int k = 0; k < 4; ++k)
    t[ty + k * 8][tx] = in[(size_t)(r0 + ty + k * 8) * 3072 + c0 + tx];
  __syncthreads();
#pragma unroll
  for (int k = 0; k < 4; ++k)
    out[(size_t)(c0 + ty + k * 8) * 2048 + r0 + tx] = t[tx][ty + k * 8];
}

__global__ __launch_bounds__(256)
void cast_x_kernel(const float* __restrict__ in, unsigned short* __restrict__ out)
{
  const size_t i = ((size_t)blockIdx.x * 256 + threadIdx.x) * 4;
  const f32x4 v = *(const f32x4*)(in + i);
  uint2 pk; pk.x = pack2bf(v[0], v[1]); pk.y = pack2bf(v[2], v[3]);
  *(uint2*)(out + i) = pk;
}

extern "C" void kernel_launch(void* const* d_in, const int* in_sizes, int n_in,
                              void* d_out, int out_size, void* d_ws, size_t ws_size,
                              hipStream_t stream)
{
  (void)in_sizes; (void)n_in; (void)out_size; (void)ws_size;  // needs ws_size >= 160MB
  const float* x   = (const float*)d_in[0];
  const float* msk = (const float*)d_in[1];
  const float* Wq  = (const float*)d_in[2];
  const float* Wk  = (const float*)d_in[3];
  const float* Wv  = (const float*)d_in[4];
  const float* Wc  = (const float*)d_in[5];
  const float* bc  = (const float*)d_in[6];
  const float* W1  = (const float*)d_in[7];
  const float* b1  = (const float*)d_in[8];
  const float* W2  = (const float*)d_in[9];
  const float* b2  = (const float*)d_in[10];
  const float* g1  = (const float*)d_in[11];
  const float* be1 = (const float*)d_in[12];
  const float* g2  = (const float*)d_in[13];
  const float* be2 = (const float*)d_in[14];
  float* out = (float*)d_out;
  char* ws = (char*)d_ws;
  const size_t MB = 1u << 20;
  unsigned short* xb    = (unsigned short*)(ws + 0 * MB);
  unsigned short* wqkvt = (unsigned short*)(ws + 16 * MB);
  unsigned short* wct   = (unsigned short*)(ws + 22 * MB);
  unsigned short* w1t   = (unsigned short*)(ws + 24 * MB);
  unsigned short* w2t   = (unsigned short*)(ws + 28 * MB);
  unsigned short* qkv   = (unsigned short*)(ws + 32 * MB);
  unsigned short* vt    = (unsigned short*)(ws + 80 * MB);
  unsigned short* attnb = xb;                        // reuse after QKV GEMM
  float*          y1    = (float*)(ws + 32 * MB);    // over dead qkv
  unsigned short* h1b   = (unsigned short*)(ws + 64 * MB);
  float*          h1f   = (float*)(ws + 96 * MB);
  unsigned short* midb  = (unsigned short*)(ws + 128 * MB);

  cast_x_kernel<<<8192, 256, 0, stream>>>(x, xb);
  tcast_kernel<<<dim3(32, 32), 256, 0, stream>>>(Wq, wqkvt,               1024, 1024);
  tcast_kernel<<<dim3(32, 32), 256, 0, stream>>>(Wk, wqkvt + 1024 * 1024, 1024, 1024);
  tcast_kernel<<<dim3(32, 32), 256, 0, stream>>>(Wv, wqkvt + 2048 * 1024, 1024, 1024);
  tcast_kernel<<<dim3(32, 32), 256, 0, stream>>>(Wc, wct,                 1024, 1024);
  tcast_kernel<<<dim3(64, 32), 256, 0, stream>>>(W1, w1t,                 1024, 2048);
  tcast_kernel<<<dim3(32, 64), 256, 0, stream>>>(W2, w2t,                 2048, 1024);

  gemm_bt<0, 0, 0><<<dim3(24, 64), 256, 0, stream>>>(xb, wqkvt, qkv, nullptr,
                                                     nullptr, nullptr, 8192, 3072, 1024);
  tv_kernel<<<dim3(32, 64, 4), 256, 0, stream>>>(qkv, vt);
  attn_kernel<<<dim3(32, 64), 256, 0, stream>>>(qkv, vt, msk, attnb);
  gemm_bt<0, 1, 1><<<dim3(8, 64), 256, 0, stream>>>(attnb, wct, nullptr, y1,
                                                    bc, x, 8192, 1024, 1024);
  ln_kernel<<<8192, 256, 0, stream>>>(y1, h1f, h1b, g1, be1);
  gemm_bt<1, 0, 0><<<dim3(16, 64), 256, 0, stream>>>(h1b, w1t, midb, nullptr,
                                                     b1, nullptr, 8192, 2048, 1024);
  gemm_bt<0, 1, 1><<<dim3(8, 64), 256, 0, stream>>>(midb, w2t, nullptr, out,
                                                    b2, h1f, 8192, 1024, 2048);
  ln_kernel<<<8192, 256, 0, stream>>>(out, out, nullptr, g2, be2);
}

// Round 2
// 470.564 us; speedup vs baseline: 1.8311x; 1.8311x over previous
//
#include <hip/hip_runtime.h>
#include <hip/hip_bf16.h>

// EncoderLayer on MI355X (gfx950).
// Pipeline: cast/transpose -> QKV GEMM (bf16 MFMA) -> V-transpose -> flash attn
//           -> proj GEMM (+bc +resid) -> LN1 -> FFN1 GEMM (+b1, relu) -> FFN2 GEMM (+b2 +resid) -> LN2.
// Workspace layout (needs 160 MB): see kernel_launch.

#define DEV __device__ __forceinline__

using s16x8 = __attribute__((ext_vector_type(8))) short;   // 8 bf16 (4 VGPR) MFMA frag
using f32x4 = __attribute__((ext_vector_type(4))) float;

DEV unsigned short f2bf(float f) {            // f32 -> bf16 RNE
  unsigned u = __float_as_uint(f);
  u += 0x7fffu + ((u >> 16) & 1u);
  return (unsigned short)(u >> 16);
}
DEV unsigned pack2bf(float a, float b) {
  return (unsigned)f2bf(a) | ((unsigned)f2bf(b) << 16);
}
DEV unsigned cvt_pk_bf16(float lo, float hi) {   // 1 VALU op: dst = {bf16(lo), bf16(hi)}
  unsigned r;
  asm("v_cvt_pk_bf16_f32 %0, %1, %2" : "=v"(r) : "v"(lo), "v"(hi));
  return r;
}

typedef __attribute__((address_space(3))) unsigned lds_u32_t;
typedef const __attribute__((address_space(1))) unsigned glb_u32_t;

// async global->LDS, 16B per lane; lds dst is wave-uniform base (HW adds lane*16)
DEV void gld_lds16(const void* g, void* l) {
  __builtin_amdgcn_global_load_lds((glb_u32_t*)g, (lds_u32_t*)l, 16, 0, 0);
}

// ---------------------------------------------------------------------------
// GEMM: C[M][N] = A[M][K] * Bt[N][K]^T  (both bf16 row-major), fp32 acc.
// 128x128 tile, BK=32, 4 waves (2x2), each wave 64x64 = 4x4 16x16x32 frags.
// XCD-chunked block swizzle for L2 locality (grids here are all %8==0).
// ---------------------------------------------------------------------------
template<int RELU, int RESID, int OUTF>
__global__ __launch_bounds__(256)
void gemm_bt(const unsigned short* __restrict__ A, const unsigned short* __restrict__ Bt,
             unsigned short* __restrict__ Cb, float* __restrict__ Cf,
             const float* __restrict__ bias, const float* __restrict__ resid,
             int M, int N, int K)
{
  __shared__ unsigned short As[128 * 32];
  __shared__ unsigned short Bs[128 * 32];
  const int tid  = threadIdx.x;
  const int wave = tid >> 6, lane = tid & 63;
  const int g = lane >> 4, q = lane & 15;

  const int nwg  = gridDim.x * gridDim.y;
  const int flat = blockIdx.y * gridDim.x + blockIdx.x;
  const int rm   = (nwg & 7) ? flat : ((flat & 7) * (nwg >> 3) + (flat >> 3));
  const int m0 = (rm / gridDim.x) * 128, n0 = (rm % gridDim.x) * 128;
  const int wr = wave >> 1, wc = wave & 1;

  f32x4 acc[4][4] = {};

  const int i0 = wave * 512 + lane * 8;        // pass 0 element index in 128x32 tile
  const int i1 = 2048 + i0;                    // pass 1

  for (int kt = 0; kt < K; kt += 32) {
    gld_lds16(A  + (size_t)(m0 + (i0 >> 5)) * K + kt + (i0 & 31), As + wave * 512);
    gld_lds16(Bt + (size_t)(n0 + (i0 >> 5)) * K + kt + (i0 & 31), Bs + wave * 512);
    gld_lds16(A  + (size_t)(m0 + (i1 >> 5)) * K + kt + (i1 & 31), As + 2048 + wave * 512);
    gld_lds16(Bt + (size_t)(n0 + (i1 >> 5)) * K + kt + (i1 & 31), Bs + 2048 + wave * 512);
    __syncthreads();                            // drains vmcnt for global_load_lds
    s16x8 a[4], b[4];
#pragma unroll
    for (int m = 0; m < 4; ++m)
      a[m] = *(const s16x8*)(As + (wr * 64 + m * 16 + q) * 32 + g * 8);
#pragma unroll
    for (int n = 0; n < 4; ++n)
      b[n] = *(const s16x8*)(Bs + (wc * 64 + n * 16 + q) * 32 + g * 8);
#pragma unroll
    for (int m = 0; m < 4; ++m)
#pragma unroll
      for (int n = 0; n < 4; ++n)
        acc[m][n] = __builtin_amdgcn_mfma_f32_16x16x32_bf16(a[m], b[n], acc[m][n], 0, 0, 0);
    __syncthreads();
  }

  // epilogue: C/D layout col = lane&15, row = (lane>>4)*4 + reg
#pragma unroll
  for (int n = 0; n < 4; ++n) {
    const int col = n0 + wc * 64 + n * 16 + q;
    const float bv = bias ? bias[col] : 0.0f;
#pragma unroll
    for (int m = 0; m < 4; ++m) {
      const int row0 = m0 + wr * 64 + m * 16 + g * 4;
#pragma unroll
      for (int r = 0; r < 4; ++r) {
        float v = acc[m][n][r] + bv;
        if (RELU) v = fmaxf(v, 0.0f);
        if (RESID) v += resid[(size_t)(row0 + r) * N + col];
        if (OUTF) Cf[(size_t)(row0 + r) * N + col] = v;
        else      Cb[(size_t)(row0 + r) * N + col] = f2bf(v);
      }
    }
  }
}

// ---------------------------------------------------------------------------
// Flash attention, LDS-staged. grid (32 q-tiles, 64 bh) -> XCD-chunk remapped.
// 4 waves/block; each wave owns 16 q rows; K/V tiles [64][64] bf16 staged in
// LDS (shared by all 4 waves), double-buffered via global_load_lds w16.
// LDS chunk-XOR swizzle (chunk ^ (row&7)) applied on the GLOBAL SOURCE side
// (linear LDS dest) and on the ds_read side -> conflict-free b128 reads.
// S^T = mfma(K, Q): lane holds one query (q = lane&15). O^T = mfma(V^T, P^T).
// ---------------------------------------------------------------------------
__global__ __launch_bounds__(256, 4)
void attn_kernel(const unsigned short* __restrict__ qkv,   // [8192][3072] Q|K|V
                 const unsigned short* __restrict__ vt,    // [(b*16+h)*64+d][2048]
                 const float* __restrict__ mask,           // [4][2048][2048]
                 unsigned short* __restrict__ outb)        // [8192][1024]
{
  __shared__ unsigned short Ks[2][4096];                   // [64 kv][64 d] swizzled
  __shared__ unsigned short Vs[2][4096];                   // [64 d][64 kv] swizzled
  __shared__ unsigned short Pl[4][1024];                   // per-wave P tile
  const int tid = threadIdx.x, wave = tid >> 6, lane = tid & 63;
  const int g = lane >> 4, q = lane & 15;

  // XCD-chunked remap: 2048 blocks -> 8 XCDs x 256; each XCD owns 8 bh values.
  const int flat = blockIdx.y * 32 + blockIdx.x;
  const int rm   = (flat & 7) * 256 + (flat >> 3);
  const int qt = rm & 31, bh = rm >> 5;
  const int b = bh >> 4, h = bh & 15;
  const int qrow = qt * 64 + wave * 16;
  const size_t tok0 = (size_t)b * 2048;

  const unsigned short* Qp = qkv + (tok0 + qrow + q) * 3072 + h * 64;
  const s16x8 bq0 = *(const s16x8*)(Qp + g * 8);           // Q B-frag, k=0..31
  const s16x8 bq1 = *(const s16x8*)(Qp + 32 + g * 8);      // k=32..63
  const float* Mp = mask + ((size_t)b * 2048 + qrow + q) * 2048;

  // staging source addresses (per-lane, pre-swizzled chunk)
  const int lr = lane >> 3;                 // row within 8-row group
  const int sc = (lane & 7) ^ lr;           // swizzled chunk index
  const unsigned short* Kg = qkv + tok0 * 3072 + 1024 + h * 64
                           + (size_t)(wave * 16 + lr) * 3072 + sc * 8;
  const unsigned short* Vg = vt + ((size_t)bh * 64 + wave * 16 + lr) * 2048 + sc * 8;
  unsigned short* KsW = Ks[0] + wave * 1024;
  unsigned short* VsW = Vs[0] + wave * 1024;

  auto STAGE = [&](int buf, int t) {
    const size_t ko = (size_t)t * (64 * 3072);
    const int    vo = t * 64;
    gld_lds16(Kg + ko,            KsW + buf * 4096);
    gld_lds16(Kg + ko + 8 * 3072, KsW + buf * 4096 + 512);
    gld_lds16(Vg + vo,            VsW + buf * 4096);
    gld_lds16(Vg + vo + 8 * 2048, VsW + buf * 4096 + 512);
  };

  f32x4 ot[4] = {};
  f32x4 mkc[4], mkn[4];
  float mrun = -3.0e38f, lsum = 0.0f;
  char* Pw = (char*)&Pl[wave][0];

  STAGE(0, 0);
#pragma unroll
  for (int m2 = 0; m2 < 4; ++m2) mkc[m2] = *(const f32x4*)(Mp + m2 * 16 + g * 4);
  __syncthreads();                           // tile 0 staged

  int cur = 0;
  for (int t = 0; t < 32; ++t) {
    if (t < 31) {                            // issue next tile early; hides under compute
      STAGE(cur ^ 1, t + 1);
#pragma unroll
      for (int m2 = 0; m2 < 4; ++m2)
        mkn[m2] = *(const f32x4*)(Mp + (t + 1) * 64 + m2 * 16 + g * 4);
    }
    const unsigned short* Kt = Ks[cur];
    const unsigned short* Vt = Vs[cur];

    f32x4 st[4] = {};
    __builtin_amdgcn_s_setprio(1);
#pragma unroll
    for (int m2 = 0; m2 < 4; ++m2) {
      const unsigned short* kp = Kt + (m2 * 16 + q) * 64;
      const s16x8 ak0 = *(const s16x8*)(kp + ((g       ^ (q & 7)) * 8));
      const s16x8 ak1 = *(const s16x8*)(kp + (((g + 4) ^ (q & 7)) * 8));
      st[m2] = __builtin_amdgcn_mfma_f32_16x16x32_bf16(ak0, bq0, st[m2], 0, 0, 0);
      st[m2] = __builtin_amdgcn_mfma_f32_16x16x32_bf16(ak1, bq1, st[m2], 0, 0, 0);
    }
    __builtin_amdgcn_s_setprio(0);

    float tmax = -3.0e38f;
#pragma unroll
    for (int m2 = 0; m2 < 4; ++m2) {
#pragma unroll
      for (int r = 0; r < 4; ++r) {
        st[m2][r] = st[m2][r] * 0.125f + mkc[m2][r];
        tmax = fmaxf(tmax, st[m2][r]);
      }
    }
    tmax = fmaxf(tmax, __shfl_xor(tmax, 16));
    tmax = fmaxf(tmax, __shfl_xor(tmax, 32));
    const float mnew  = fmaxf(mrun, tmax);
    const float alpha = __expf(mrun - mnew);
    mrun = mnew;

    float rsum = 0.0f;
#pragma unroll
    for (int m2 = 0; m2 < 4; ++m2) {
#pragma unroll
      for (int r = 0; r < 4; ++r) {
        st[m2][r] = __expf(st[m2][r] - mnew);
        rsum += st[m2][r];
      }
      const int bir  = m2 * 32 + g * 8;      // byte pos of this 4-kv group in P row
      const int addr = q * 128 + ((((bir >> 4) ^ (q & 7))) << 4) + (bir & 15);
      uint2 pk;
      pk.x = cvt_pk_bf16(st[m2][0], st[m2][1]);
      pk.y = cvt_pk_bf16(st[m2][2], st[m2][3]);
      *(uint2*)(Pw + addr) = pk;             // same-wave DS FIFO: no barrier needed
    }
    rsum += __shfl_xor(rsum, 16);
    rsum += __shfl_xor(rsum, 32);
    lsum = lsum * alpha + rsum;
#pragma unroll
    for (int m = 0; m < 4; ++m) {
      ot[m][0] *= alpha; ot[m][1] *= alpha; ot[m][2] *= alpha; ot[m][3] *= alpha;
    }

    __builtin_amdgcn_s_setprio(1);
#pragma unroll
    for (int kb = 0; kb < 2; ++kb) {
      const int blk = (kb * 4 + g) ^ (q & 7);
      const s16x8 pb = *(const s16x8*)(Pw + q * 128 + blk * 16);
#pragma unroll
      for (int m = 0; m < 4; ++m) {
        const s16x8 av = *(const s16x8*)(Vt + (m * 16 + q) * 64 + blk * 8);
        ot[m] = __builtin_amdgcn_mfma_f32_16x16x32_bf16(av, pb, ot[m], 0, 0, 0);
      }
    }
    __builtin_amdgcn_s_setprio(0);

#pragma unroll
    for (int m2 = 0; m2 < 4; ++m2) mkc[m2] = mkn[m2];
    __syncthreads();                         // drains vmcnt: next tile staged; guards dbuf reuse
    cur ^= 1;
  }

  // finalize: O[q][d] = ot/lsum; transpose through LDS for coalesced 16B stores
  const float inv = 1.0f / lsum;
#pragma unroll
  for (int m = 0; m < 4; ++m) {
    const int bir  = m * 32 + g * 8;
    const int addr = q * 128 + (((bir >> 4) ^ (q & 7)) << 4) + (bir & 15);
    uint2 pk;
    pk.x = cvt_pk_bf16(ot[m][0] * inv, ot[m][1] * inv);
    pk.y = cvt_pk_bf16(ot[m][2] * inv, ot[m][3] * inv);
    *(uint2*)(Pw + addr) = pk;
  }
#pragma unroll
  for (int p = 0; p < 2; ++p) {
    const int c  = p * 64 + lane;
    const int qq = c >> 3, cc = c & 7;
    const int blk = cc ^ (qq & 7);
    const s16x8 vv = *(const s16x8*)(Pw + qq * 128 + blk * 16);
    *(s16x8*)(outb + (tok0 + qrow + qq) * 1024 + h * 64 + cc * 8) = vv;
  }
}

// ---------------------------------------------------------------------------
// Row LayerNorm over D=1024. One 256-thread block per row. In-place safe.
// ---------------------------------------------------------------------------
__global__ __launch_bounds__(256)
void ln_kernel(const float* __restrict__ in, float* __restrict__ outf,
               unsigned short* __restrict__ outb,
               const float* __restrict__ gam, const float* __restrict__ bet)
{
  __shared__ float red[8];
  const int row = blockIdx.x, tid = threadIdx.x;
  const f32x4 v = *(const f32x4*)(in + (size_t)row * 1024 + tid * 4);
  float s  = v[0] + v[1] + v[2] + v[3];
  float ss = v[0]*v[0] + v[1]*v[1] + v[2]*v[2] + v[3]*v[3];
#pragma unroll
  for (int o = 1; o < 64; o <<= 1) { s += __shfl_xor(s, o); ss += __shfl_xor(ss, o); }
  if ((tid & 63) == 0) { red[tid >> 6] = s; red[4 + (tid >> 6)] = ss; }
  __syncthreads();
  s  = red[0] + red[1] + red[2] + red[3];
  ss = red[4] + red[5] + red[6] + red[7];
  const float mean = s * (1.0f / 1024.0f);
  const float var  = ss * (1.0f / 1024.0f) - mean * mean;
  const float rstd = rsqrtf(var + 1e-5f);
  const f32x4 gm = *(const f32x4*)(gam + tid * 4);
  const f32x4 bt = *(const f32x4*)(bet + tid * 4);
  f32x4 o;
#pragma unroll
  for (int j = 0; j < 4; ++j) o[j] = (v[j] - mean) * rstd * gm[j] + bt[j];
  if (outf) *(f32x4*)(outf + (size_t)row * 1024 + tid * 4) = o;
  if (outb) {
    uint2 pk; pk.x = pack2bf(o[0], o[1]); pk.y = pack2bf(o[2], o[3]);
    *(uint2*)(outb + (size_t)row * 1024 + tid * 4) = pk;
  }
}

// f32 [R][C] -> bf16 [C][R]
__global__ __launch_bounds__(256)
void tcast_kernel(const float* __restrict__ in, unsigned short* __restrict__ out, int R, int C)
{
  __shared__ float t[32][33];
  const int tx = threadIdx.x & 31, ty = threadIdx.x >> 5;
  const int c0 = blockIdx.x * 32, r0 = blockIdx.y * 32;
#pragma unroll
  for (int k = 0; k < 4; ++k)
    t[ty + k * 8][tx] = in[(size_t)(r0 + ty + k * 8) * C + c0 + tx];
  __syncthreads();
#pragma unroll
  for (int k = 0; k < 4; ++k)
    out[(size_t)(c0 + ty + k * 8) * R + r0 + tx] = f2bf(t[tx][ty + k * 8]);
}

// V part of qkv (cols 2048..3071, per batch) -> vt[(b*16+h)*64+d][token]
__global__ __launch_bounds__(256)
void tv_kernel(const unsigned short* __restrict__ qkv, unsigned short* __restrict__ vt)
{
  __shared__ unsigned short t[32][33];
  const int tx = threadIdx.x & 31, ty = threadIdx.x >> 5;
  const int c0 = blockIdx.x * 32, r0 = blockIdx.y * 32, b = blockIdx.z;
  const unsigned short* in = qkv + (size_t)b * 2048 * 3072 + 2048;
  unsigned short* out = vt + (size_t)b * 1024 * 2048;
#pragma unroll
  for (int k = 0; k < 4; ++k)
    t[ty + k * 8][tx] = in[(size_t)(r0 + ty + k * 8) * 3072 + c0 + tx];
  __syncthreads();
#pragma unroll
  for (int k = 0; k < 4; ++k)
    out[(size_t)(c0 + ty + k * 8) * 2048 + r0 + tx] = t[tx][ty + k * 8];
}

__global__ __launch_bounds__(256)
void cast_x_kernel(const float* __restrict__ in, unsigned short* __restrict__ out)
{
  const size_t i = ((size_t)blockIdx.x * 256 + threadIdx.x) * 4;
  const f32x4 v = *(const f32x4*)(in + i);
  uint2 pk; pk.x = pack2bf(v[0], v[1]); pk.y = pack2bf(v[2], v[3]);
  *(uint2*)(out + i) = pk;
}

extern "C" void kernel_launch(void* const* d_in, const int* in_sizes, int n_in,
                              void* d_out, int out_size, void* d_ws, size_t ws_size,
                              hipStream_t stream)
{
  (void)in_sizes; (void)n_in; (void)out_size; (void)ws_size;  // needs ws_size >= 160MB
  const float* x   = (const float*)d_in[0];
  const float* msk = (const float*)d_in[1];
  const float* Wq  = (const float*)d_in[2];
  const float* Wk  = (const float*)d_in[3];
  const float* Wv  = (const float*)d_in[4];
  const float* Wc  = (const float*)d_in[5];
  const float* bc  = (const float*)d_in[6];
  const float* W1  = (const float*)d_in[7];
  const float* b1  = (const float*)d_in[8];
  const float* W2  = (const float*)d_in[9];
  const float* b2  = (const float*)d_in[10];
  const float* g1  = (const float*)d_in[11];
  const float* be1 = (const float*)d_in[12];
  const float* g2  = (const float*)d_in[13];
  const float* be2 = (const float*)d_in[14];
  float* out = (float*)d_out;
  char* ws = (char*)d_ws;
  const size_t MB = 1u << 20;
  unsigned short* xb    = (unsigned short*)(ws + 0 * MB);
  unsigned short* wqkvt = (unsigned short*)(ws + 16 * MB);
  unsigned short* wct   = (unsigned short*)(ws + 22 * MB);
  unsigned short* w1t   = (unsigned short*)(ws + 24 * MB);
  unsigned short* w2t   = (unsigned short*)(ws + 28 * MB);
  unsigned short* qkv   = (unsigned short*)(ws + 32 * MB);
  unsigned short* vt    = (unsigned short*)(ws + 80 * MB);
  unsigned short* attnb = xb;                        // reuse after QKV GEMM
  float*          y1    = (float*)(ws + 32 * MB);    // over dead qkv
  unsigned short* h1b   = (unsigned short*)(ws + 64 * MB);
  float*          h1f   = (float*)(ws + 96 * MB);
  unsigned short* midb  = (unsigned short*)(ws + 128 * MB);

  cast_x_kernel<<<8192, 256, 0, stream>>>(x, xb);
  tcast_kernel<<<dim3(32, 32), 256, 0, stream>>>(Wq, wqkvt,               1024, 1024);
  tcast_kernel<<<dim3(32, 32), 256, 0, stream>>>(Wk, wqkvt + 1024 * 1024, 1024, 1024);
  tcast_kernel<<<dim3(32, 32), 256, 0, stream>>>(Wv, wqkvt + 2048 * 1024, 1024, 1024);
  tcast_kernel<<<dim3(32, 32), 256, 0, stream>>>(Wc, wct,                 1024, 1024);
  tcast_kernel<<<dim3(64, 32), 256, 0, stream>>>(W1, w1t,                 1024, 2048);
  tcast_kernel<<<dim3(32, 64), 256, 0, stream>>>(W2, w2t,                 2048, 1024);

  gemm_bt<0, 0, 0><<<dim3(24, 64), 256, 0, stream>>>(xb, wqkvt, qkv, nullptr,
                                                     nullptr, nullptr, 8192, 3072, 1024);
  tv_kernel<<<dim3(32, 64, 4), 256, 0, stream>>>(qkv, vt);
  attn_kernel<<<dim3(32, 64), 256, 0, stream>>>(qkv, vt, msk, attnb);
  gemm_bt<0, 1, 1><<<dim3(8, 64), 256, 0, stream>>>(attnb, wct, nullptr, y1,
                                                    bc, x, 8192, 1024, 1024);
  ln_kernel<<<8192, 256, 0, stream>>>(y1, h1f, h1b, g1, be1);
  gemm_bt<1, 0, 0><<<dim3(16, 64), 256, 0, stream>>>(h1b, w1t, midb, nullptr,
                                                     b1, nullptr, 8192, 2048, 1024);
  gemm_bt<0, 1, 1><<<dim3(8, 64), 256, 0, stream>>>(midb, w2t, nullptr, out,
                                                    b2, h1f, 8192, 1024, 2048);
  ln_kernel<<<8192, 256, 0, stream>>>(out, out, nullptr, g2, be2);
}